// Round 8
// baseline (126.050 us; speedup 1.0000x reference)
//
#include <hip/hip_runtime.h>

#define DIM 256
#define NHEADS 8
#define HDIM 32

typedef _Float16 half8_t __attribute__((ext_vector_type(8)));
typedef _Float16 half4_t __attribute__((ext_vector_type(4)));
typedef float float4_t __attribute__((ext_vector_type(4)));

__device__ __forceinline__ void gload_lds16(const void* g, void* l) {
    __builtin_amdgcn_global_load_lds((const __attribute__((address_space(1))) void*)g,
                                     (__attribute__((address_space(3))) void*)l,
                                     16, 0, 0);
}

// ---------------------------------------------------------------------------
// prep: (a) x fp32 -> fp16 flat; (b) Wqkv [256,768] -> WqT [768,256] fp16;
//       (c) Wout [256,256] -> WoT [256,256] fp16 (transposed for B-frags).
// ---------------------------------------------------------------------------
__global__ __launch_bounds__(256) void prep(const float* __restrict__ x,
                                            const float* __restrict__ Wqkv,
                                            const float* __restrict__ Wout,
                                            _Float16* __restrict__ xh,
                                            _Float16* __restrict__ WqT,
                                            _Float16* __restrict__ WoT) {
    __shared__ float ts[32][33];
    const int bid = blockIdx.x, t = threadIdx.x;
    if (bid < 1024) {
        size_t idx = (size_t)bid * 2048 + (size_t)t * 8;
        float tmp[8];
        *reinterpret_cast<float4*>(tmp)     = *reinterpret_cast<const float4*>(x + idx);
        *reinterpret_cast<float4*>(tmp + 4) = *reinterpret_cast<const float4*>(x + idx + 4);
        half8_t h;
        #pragma unroll
        for (int j = 0; j < 8; ++j) h[j] = (_Float16)tmp[j];
        *reinterpret_cast<half8_t*>(xh + idx) = h;
    } else {
        const float* src; _Float16* dst; int K, N, kb, nb;
        if (bid < 1024 + 192) { int b2 = bid - 1024; src = Wqkv; dst = WqT; K = 256; N = 768; nb = b2 % 24; kb = b2 / 24; }
        else                  { int b3 = bid - 1216; src = Wout; dst = WoT; K = 256; N = 256; nb = b3 % 8;  kb = b3 / 8; }
        const int tx = t & 31, ty = t >> 5;
        #pragma unroll
        for (int i = 0; i < 4; ++i) {
            int k = kb * 32 + ty + i * 8;
            ts[ty + i * 8][tx] = src[(size_t)k * N + nb * 32 + tx];
        }
        __syncthreads();
        #pragma unroll
        for (int i = 0; i < 4; ++i) {
            int nl = ty + i * 8;
            dst[(size_t)(nb * 32 + nl) * K + kb * 32 + tx] = (_Float16)ts[tx][nl];
        }
    }
}

// ---------------------------------------------------------------------------
// qkv GEMM: C = xh[8192,256] @ WqT[768,256]^T.  64x128 tile, BK=32, 4 waves
// (each 32x64), m97-style global_load_lds staging. 768 blocks (3/CU).
// Epilogue routes by n-range:
//   n<256   -> Q  : qh[row][col] fp16 (row-major [8192,256])
//   256-511 -> K  : kpack[bh][key][hd]   (contiguous 1KB per 16-key frag)
//   512-767 -> V  : vp[bh][key/32][hd][key%32] (contiguous 1KB per PV frag)
// ---------------------------------------------------------------------------
__global__ __launch_bounds__(256) void gemm_qkv(const _Float16* __restrict__ A,
                                                const _Float16* __restrict__ BT,
                                                _Float16* __restrict__ qh,
                                                _Float16* __restrict__ kpack,
                                                _Float16* __restrict__ vp) {
    __shared__ alignas(16) _Float16 As[64 * 32];
    __shared__ alignas(16) _Float16 Bs[128 * 32];
    const int t = threadIdx.x, lane = t & 63, wave = t >> 6;
    const int l16 = lane & 15, quad = lane >> 4;
    const int m0 = blockIdx.y * 64, n0 = blockIdx.x * 128;
    const int wr = (wave >> 1) * 32, wc = (wave & 1) * 64;
    const int K = 256;

    float4_t acc[2][4];
    #pragma unroll
    for (int i = 0; i < 2; ++i)
        #pragma unroll
        for (int j = 0; j < 4; ++j) acc[i][j] = (float4_t){0.f, 0.f, 0.f, 0.f};

    const int srow = lane >> 2;        // 0..15
    const int scol = (lane & 3) * 8;   // halves

    for (int k0 = 0; k0 < K; k0 += 32) {
        // A: 4 chunks of 16 rows (wave w -> chunk w); B: 8 chunks (w, w+4).
        gload_lds16(A  + (size_t)(m0 + wave * 16 + srow) * K + k0 + scol, As + wave * 512);
        gload_lds16(BT + (size_t)(n0 + wave * 16 + srow) * K + k0 + scol, Bs + wave * 512);
        gload_lds16(BT + (size_t)(n0 + 64 + wave * 16 + srow) * K + k0 + scol, Bs + 2048 + wave * 512);
        __syncthreads();
        half8_t af[2], bf[4];
        #pragma unroll
        for (int i = 0; i < 2; ++i)
            af[i] = *reinterpret_cast<const half8_t*>(As + (wr + i * 16 + l16) * 32 + quad * 8);
        #pragma unroll
        for (int j = 0; j < 4; ++j)
            bf[j] = *reinterpret_cast<const half8_t*>(Bs + (wc + j * 16 + l16) * 32 + quad * 8);
        #pragma unroll
        for (int i = 0; i < 2; ++i)
            #pragma unroll
            for (int j = 0; j < 4; ++j)
                acc[i][j] = __builtin_amdgcn_mfma_f32_16x16x32_f16(af[i], bf[j], acc[i][j], 0, 0, 0);
        __syncthreads();
    }

    const int bb = m0 >> 11;
    if (n0 < 256) {
        // Q: plain row-major store
        #pragma unroll
        for (int i = 0; i < 2; ++i)
            #pragma unroll
            for (int r = 0; r < 4; ++r) {
                int row = m0 + wr + i * 16 + quad * 4 + r;
                #pragma unroll
                for (int j = 0; j < 4; ++j)
                    qh[(size_t)row * 256 + n0 + wc + j * 16 + l16] = (_Float16)acc[i][j][r];
            }
    } else if (n0 < 512) {
        // K: kpack[bh][tok][d]
        #pragma unroll
        for (int i = 0; i < 2; ++i)
            #pragma unroll
            for (int r = 0; r < 4; ++r) {
                int tok = (m0 & 2047) + wr + i * 16 + quad * 4 + r;
                #pragma unroll
                for (int j = 0; j < 4; ++j) {
                    int kc = n0 + wc + j * 16 + l16 - 256;
                    int hh = kc >> 5, dd = kc & 31;
                    kpack[((size_t)(bb * NHEADS + hh) * 2048 + tok) * 32 + dd] =
                        (_Float16)acc[i][j][r];
                }
            }
    } else {
        // V: vp[bh][tok/32][d][tok%32], 4 tokens per half4 store
        #pragma unroll
        for (int i = 0; i < 2; ++i) {
            int tok0 = (m0 & 2047) + wr + i * 16 + quad * 4;
            int chunk = tok0 >> 5, tl = tok0 & 31;
            #pragma unroll
            for (int j = 0; j < 4; ++j) {
                int vc = n0 + wc + j * 16 + l16 - 512;
                int hh = vc >> 5, dd = vc & 31;
                half4_t p;
                #pragma unroll
                for (int r = 0; r < 4; ++r) p[r] = (_Float16)acc[i][j][r];
                *reinterpret_cast<half4_t*>(
                    vp + (((size_t)(bb * NHEADS + hh) * 64 + chunk) * 32 + dd) * 32 + tl) = p;
            }
        }
    }
}

// ---------------------------------------------------------------------------
// MFMA flash attention v7: 64 q/wave, key-split x2, packed K/V layouts so
// every fragment load is lane-contiguous (1KB per wave-load).
// Grid: 512 = (b,h) x 8 q-blocks(256) x 2 key-halves(1024). Zero barriers.
// S^T = mfma(kf,qf); E round-trip through per-wave es[64][40] (b64 w, b128 r).
// Partials: NUM fp16 (unnormalized), DEN fp32; combined in gemm2's A-staging.
// ---------------------------------------------------------------------------
__global__ __launch_bounds__(256, 2) void attn_v7(const _Float16* __restrict__ qh,
                                                  const _Float16* __restrict__ kpack,
                                                  const _Float16* __restrict__ vp,
                                                  _Float16* __restrict__ NUM,
                                                  float* __restrict__ DEN) {
    __shared__ alignas(16) _Float16 es[4][64][40];
    const int bid = blockIdx.x;
    const int kh = bid & 1;
    const int qb = (bid >> 1) & 7;
    const int bh = bid >> 4;
    const int b = bh >> 3, h = bh & 7;
    const int t = threadIdx.x, lane = t & 63, wave = t >> 6;
    const int l16 = lane & 15, quad = lane >> 4;
    const float scale = 0.17677669529663687f;  // 32^-0.5
    const int bN = b * 2048;
    const int q0w = qb * 256 + wave * 64;
    const int kbeg = kh * 1024;

    // Q fragments (B-operand of S^T): 4 groups of 16 q.
    half8_t qf[4];
    {
        const _Float16* qrow = qh + (size_t)(bN + q0w + l16) * 256 + h * HDIM + quad * 8;
        #pragma unroll
        for (int g = 0; g < 4; ++g)
            qf[g] = *reinterpret_cast<const half8_t*>(qrow + (size_t)g * 16 * 256);
    }

    const _Float16* kb_ = kpack + (size_t)bh * 65536;   // [2048][32]
    const _Float16* vb_ = vp + (size_t)bh * 65536;      // [64][32][32]

    float4_t num[4][2];
    #pragma unroll
    for (int g = 0; g < 4; ++g)
        #pragma unroll
        for (int dt = 0; dt < 2; ++dt) num[g][dt] = (float4_t){0.f, 0.f, 0.f, 0.f};
    float ds[4] = {0.f, 0.f, 0.f, 0.f};
    _Float16* esw = &es[wave][0][0];
    const float4_t z = {0.f, 0.f, 0.f, 0.f};

    for (int k0 = kbeg; k0 < kbeg + 1024; k0 += 64) {
        // K frags: 4 x (16 keys x 32 hd) = 4 contiguous 1KB wave-loads.
        half8_t kf[4], vf[4];
        #pragma unroll
        for (int j = 0; j < 4; ++j)
            kf[j] = *reinterpret_cast<const half8_t*>(
                kb_ + (size_t)(k0 + j * 16 + l16) * 32 + quad * 8);
        // V frags: 2 chunks x 2 hd-halves, each contiguous 1KB.
        const int c0 = k0 >> 5;
        #pragma unroll
        for (int s = 0; s < 2; ++s)
            #pragma unroll
            for (int m = 0; m < 2; ++m)
                vf[s * 2 + m] = *reinterpret_cast<const half8_t*>(
                    vb_ + ((size_t)(c0 + s) * 32 + m * 16 + l16) * 32 + quad * 8);

        // S^T = K Q^T : lane holds S^T[key=kb*16+quad*4+r][q=q0w+g*16+l16]
        float4_t st[4][4];
        #pragma unroll
        for (int kb = 0; kb < 4; ++kb)
            #pragma unroll
            for (int g = 0; g < 4; ++g)
                st[kb][g] = __builtin_amdgcn_mfma_f32_16x16x32_f16(kf[kb], qf[g], z, 0, 0, 0);

        // e = exp(s*scale); accumulate denom; pack fp16 half4 per (kb,g).
        half4_t ep[4][4];
        #pragma unroll
        for (int kb = 0; kb < 4; ++kb)
            #pragma unroll
            for (int g = 0; g < 4; ++g)
                #pragma unroll
                for (int r = 0; r < 4; ++r) {
                    float e = __expf(st[kb][g][r] * scale);
                    ds[g] += e;
                    ep[kb][g][r] = (_Float16)e;
                }

        // Two 32-key chunks: E -> LDS (b64), E A-frags back (b128), PV MFMAs.
        #pragma unroll
        for (int s = 0; s < 2; ++s) {
            #pragma unroll
            for (int tt = 0; tt < 2; ++tt)
                #pragma unroll
                for (int g = 0; g < 4; ++g)
                    *reinterpret_cast<half4_t*>(
                        esw + (g * 16 + l16) * 40 + tt * 16 + quad * 4) = ep[s * 2 + tt][g];

            #pragma unroll
            for (int g = 0; g < 4; ++g) {
                half8_t ef = *reinterpret_cast<const half8_t*>(
                    esw + (g * 16 + l16) * 40 + quad * 8);
                num[g][0] = __builtin_amdgcn_mfma_f32_16x16x32_f16(ef, vf[s * 2],     num[g][0], 0, 0, 0);
                num[g][1] = __builtin_amdgcn_mfma_f32_16x16x32_f16(ef, vf[s * 2 + 1], num[g][1], 0, 0, 0);
            }
        }
    }

    // denom partials: sum the 4 key-quads per q column.
    #pragma unroll
    for (int g = 0; g < 4; ++g) {
        ds[g] += __shfl_xor(ds[g], 16, 64);
        ds[g] += __shfl_xor(ds[g], 32, 64);
    }

    _Float16* ob = NUM + (size_t)kh * 2097152 + (size_t)(bN + q0w) * DIM + h * HDIM;
    #pragma unroll
    for (int g = 0; g < 4; ++g)
        #pragma unroll
        for (int r = 0; r < 4; ++r) {
            size_t ro = (size_t)(g * 16 + quad * 4 + r) * DIM;
            ob[ro + l16]      = (_Float16)num[g][0][r];
            ob[ro + 16 + l16] = (_Float16)num[g][1][r];
        }
    if (quad == 0) {
        #pragma unroll
        for (int g = 0; g < 4; ++g)
            DEN[kh * 65536 + bh * 2048 + q0w + g * 16 + l16] = ds[g];
    }
}

// ---------------------------------------------------------------------------
// gemm2 + combine fused: out = [(N0+N1)*rcp(D0+D1+eps)] @ WoT^T + bout (fp32).
// 64x64 tile, BK=32, 4 waves (32x32 each). A staged via VALU (combine math
// during staging, per-row/per-head reciprocals hoisted); B staged via DMA.
// Grid 512 blocks (2/CU).
// ---------------------------------------------------------------------------
__global__ __launch_bounds__(256) void gemm2c(const _Float16* __restrict__ NUM,
                                              const float* __restrict__ DEN,
                                              const _Float16* __restrict__ BT,
                                              const float* __restrict__ bias,
                                              float* __restrict__ out) {
    __shared__ alignas(16) _Float16 As[64 * 32];
    __shared__ alignas(16) _Float16 Bs[64 * 32];
    const int t = threadIdx.x, lane = t & 63, wave = t >> 6;
    const int l16 = lane & 15, quad = lane >> 4;
    const int m0 = blockIdx.y * 64, n0 = blockIdx.x * 64;
    const int wr = (wave >> 1) * 32, wc = (wave & 1) * 32;
    const int bb = m0 >> 11;

    // staging coords
    const int arow = t >> 2;            // 0..63
    const int acol = (t & 3) * 8;       // halves
    const int myrow = m0 + arow;
    // hoisted reciprocal denominators for this thread's A row, all 8 heads
    _Float16 rcp8[8];
    #pragma unroll
    for (int hh = 0; hh < 8; ++hh) {
        int di = (bb * 8 + hh) * 2048 + (myrow & 2047);
        rcp8[hh] = (_Float16)(1.f / (DEN[di] + DEN[di + 65536] + 1e-6f));
    }
    const _Float16* np = NUM + (size_t)myrow * 256 + acol;

    float4_t acc[2][2];
    #pragma unroll
    for (int i = 0; i < 2; ++i)
        #pragma unroll
        for (int j = 0; j < 2; ++j) acc[i][j] = (float4_t){0.f, 0.f, 0.f, 0.f};

    for (int k0 = 0; k0 < 256; k0 += 32) {
        // A: combine partials during staging (head uniform per k-iter)
        half8_t n0h = *reinterpret_cast<const half8_t*>(np + k0);
        half8_t n1h = *reinterpret_cast<const half8_t*>(np + k0 + 2097152);
        *reinterpret_cast<half8_t*>(As + arow * 32 + acol) = (n0h + n1h) * rcp8[k0 >> 5];
        // B: DMA 4KB
        gload_lds16(BT + (size_t)(n0 + arow) * 256 + k0 + acol, Bs + t * 8);
        __syncthreads();
        half8_t af[2], bf[2];
        #pragma unroll
        for (int i = 0; i < 2; ++i)
            af[i] = *reinterpret_cast<const half8_t*>(As + (wr + i * 16 + l16) * 32 + quad * 8);
        #pragma unroll
        for (int j = 0; j < 2; ++j)
            bf[j] = *reinterpret_cast<const half8_t*>(Bs + (wc + j * 16 + l16) * 32 + quad * 8);
        #pragma unroll
        for (int i = 0; i < 2; ++i)
            #pragma unroll
            for (int j = 0; j < 2; ++j)
                acc[i][j] = __builtin_amdgcn_mfma_f32_16x16x32_f16(af[i], bf[j], acc[i][j], 0, 0, 0);
        __syncthreads();
    }

    #pragma unroll
    for (int i = 0; i < 2; ++i)
        #pragma unroll
        for (int r = 0; r < 4; ++r) {
            int row = m0 + wr + i * 16 + quad * 4 + r;
            #pragma unroll
            for (int j = 0; j < 2; ++j) {
                int col = n0 + wc + j * 16 + l16;
                out[(size_t)row * 256 + col] = acc[i][j][r] + bias[col];
            }
        }
}

extern "C" void kernel_launch(void* const* d_in, const int* in_sizes, int n_in,
                              void* d_out, int out_size, void* d_ws, size_t ws_size,
                              hipStream_t stream) {
    const float* x    = (const float*)d_in[0];
    const float* Wqkv = (const float*)d_in[1];
    const float* Wout = (const float*)d_in[2];
    const float* bout = (const float*)d_in[3];
    float* out = (float*)d_out;
    const int M = 8192;

    _Float16* xh    = (_Float16*)d_ws;                 // [8192,256]
    _Float16* WqT   = xh + (size_t)M * DIM;            // [768,256]
    _Float16* WoT   = WqT + 768 * 256;                 // [256,256]
    _Float16* qh    = WoT + 256 * 256;                 // [8192,256]
    _Float16* kpack = qh + (size_t)M * DIM;            // [32][2048][32]
    _Float16* vp    = kpack + (size_t)32 * 2048 * 32;  // [32][64][32][32]
    _Float16* NUM   = vp + (size_t)32 * 2048 * 32;     // [2][8192,256]
    float*    DEN   = (float*)(NUM + (size_t)2 * M * DIM);  // [2][65536]

    hipLaunchKernelGGL(prep, dim3(1280), dim3(256), 0, stream, x, Wqkv, Wout, xh, WqT, WoT);
    hipLaunchKernelGGL(gemm_qkv, dim3(6, 128), dim3(256), 0, stream, xh, WqT, qh, kpack, vp);
    hipLaunchKernelGGL(attn_v7, dim3(512), dim3(256), 0, stream, qh, kpack, vp, NUM, DEN);
    hipLaunchKernelGGL(gemm2c, dim3(4, 128), dim3(256), 0, stream, NUM, DEN, WoT, bout, out);
}